// Round 8
// baseline (244.092 us; speedup 1.0000x reference)
//
#include <hip/hip_runtime.h>

// NCC loss, Round 7 (resubmit): the known-good streaming-reduction recipe.
// Rounds 1/4/5/6 (one-shot grids, reg pipelines, global_load_lds+vmcnt) all
// pinned at ~93-100us (~2.9 TB/s). Reference memory-bound kernels on this
// chip (RMSNorm/LN, 82-86% of 6.3 TB/s) use: ~2048 blocks x 256 threads,
// grid-stride, plain dwordx4 register loads, low VGPR, full occupancy.
// This kernel replicates that shape exactly.

#define NB   16
#define VOL  (64 * 128 * 128)     // 1048576 elems per batch
#define BPB  128                  // blocks per batch (grid.x) -> 2048 total
#define TPB  256
#define ITER 8                    // grid-stride iterations per thread
#define NPB  (NB * BPB)           // 2048 block-partial slots

static_assert((long long)BPB * TPB * 4 * ITER == (long long)VOL, "coverage");

__device__ __forceinline__ double wave_reduce(double v) {
#pragma unroll
    for (int off = 32; off > 0; off >>= 1) v += __shfl_down(v, off, 64);
    return v;
}

// f32 threshold TH such that (f32 x < TH) <=> ((double)x < 0.247) exactly.
__device__ __forceinline__ float mask_thresh() {
    const float c = 0.247f;
    if ((double)c < 0.247) return __uint_as_float(__float_as_uint(c) + 1u);
    return c;
}

__global__ __launch_bounds__(TPB) void ncc_partial(
    const float* __restrict__ I, const float* __restrict__ J,
    const int* __restrict__ CI, const int* __restrict__ CJ,
    double* __restrict__ part)
{
    const int b = blockIdx.y, bx = blockIdx.x;
    const int tid = threadIdx.x;

    const float4* __restrict__ I4 = reinterpret_cast<const float4*>(I);
    const float4* __restrict__ J4 = reinterpret_cast<const float4*>(J);
    const int4*   __restrict__ C4 = reinterpret_cast<const int4*>(CI);
    const int4*   __restrict__ D4 = reinterpret_cast<const int4*>(CJ);

    const size_t batchq = (size_t)b * (VOL / 4);
    const float TH = mask_thresh();

    double aI = 0, aJ = 0, aI2 = 0, aJ2 = 0, aIJ = 0;
    int cnt = 0;

#pragma unroll
    for (int it = 0; it < ITER; ++it) {
        // grid-stride: iteration stride = BPB*TPB quads (512 KB), coalesced
        const size_t q = batchq + (size_t)it * (BPB * TPB) + (size_t)bx * TPB + tid;
        float4 iv = I4[q];
        float4 jv = J4[q];
        int4   cv = C4[q];
        int4   dv = D4[q];

        float pI  = (iv.x + iv.y) + (iv.z + iv.w);
        float pJ  = (jv.x + jv.y) + (jv.z + jv.w);
        float pI2 = fmaf(iv.x, iv.x, fmaf(iv.y, iv.y, fmaf(iv.z, iv.z, iv.w * iv.w)));
        float pJ2 = fmaf(jv.x, jv.x, fmaf(jv.y, jv.y, fmaf(jv.z, jv.z, jv.w * jv.w)));
        float pIJ = fmaf(iv.x, jv.x, fmaf(iv.y, jv.y, fmaf(iv.z, jv.z, iv.w * jv.w)));

        int pc = 0;
        bool zI, zJ;
        zI = (iv.x < TH) && (cv.x > 0); zJ = (jv.x < TH) && (dv.x > 0); pc += (!zI && !zJ);
        zI = (iv.y < TH) && (cv.y > 0); zJ = (jv.y < TH) && (dv.y > 0); pc += (!zI && !zJ);
        zI = (iv.z < TH) && (cv.z > 0); zJ = (jv.z < TH) && (dv.z > 0); pc += (!zI && !zJ);
        zI = (iv.w < TH) && (cv.w > 0); zJ = (jv.w < TH) && (dv.w > 0); pc += (!zI && !zJ);

        aI  += (double)pI;
        aJ  += (double)pJ;
        aI2 += (double)pI2;
        aJ2 += (double)pJ2;
        aIJ += (double)pIJ;
        cnt += pc;
    }

    double v[6] = {aI, aJ, aI2, aJ2, aIJ, (double)cnt};
#pragma unroll
    for (int q = 0; q < 6; ++q) v[q] = wave_reduce(v[q]);

    __shared__ double sh[TPB / 64][6];
    const int wave = tid >> 6, lane = tid & 63;
    if (lane == 0) {
#pragma unroll
        for (int q = 0; q < 6; ++q) sh[wave][q] = v[q];
    }
    __syncthreads();

    if (tid == 0) {
        const int gb = b * BPB + bx;
#pragma unroll
        for (int q = 0; q < 6; ++q) {
            double o = 0.0;
            for (int w = 0; w < TPB / 64; ++w) o += sh[w][q];
            part[(size_t)q * NPB + gb] = o;   // SoA: coalesced for final pass
        }
    }
}

__global__ __launch_bounds__(1024) void ncc_final(
    const double* __restrict__ part, float* __restrict__ outp)
{
    const int tid = threadIdx.x;
    const int w = tid >> 6;     // wave w <-> batch w (16 waves)
    const int l = tid & 63;

    // BPB=128 partials per batch: 2 per lane
    double v[6];
#pragma unroll
    for (int q = 0; q < 6; ++q) {
        const size_t base = (size_t)q * NPB + (size_t)w * BPB;
        v[q] = part[base + l] + part[base + 64 + l];
    }
#pragma unroll
    for (int q = 0; q < 6; ++q) v[q] = wave_reduce(v[q]);

    __shared__ double acc[NB];
    if (l == 0) {
        const double W = (double)VOL;
        double uI = v[0] / W, uJ = v[1] / W;
        double cross = v[4] - uJ * v[0] - uI * v[1] + uI * uJ * W;
        double Ivar  = v[2] - 2.0 * uI * v[0] + uI * uI * W;
        double Jvar  = v[3] - 2.0 * uJ * v[1] + uJ * uJ * W;
        double cc = (cross * cross) / (Ivar * Jvar + 1e-5);
        acc[w] = -cc * v[5];
    }
    __syncthreads();

    if (tid == 0) {
        double t = 0.0;
        for (int b = 0; b < NB; ++b) t += acc[b];
        outp[0] = (float)(t / ((double)NB * (double)VOL));
    }
}

extern "C" void kernel_launch(void* const* d_in, const int* in_sizes, int n_in,
                              void* d_out, int out_size, void* d_ws, size_t ws_size,
                              hipStream_t stream)
{
    const float* I  = (const float*)d_in[0];   // out
    const float* J  = (const float*)d_in[1];   // y_pred
    const int*   CI = (const int*)d_in[2];     // out_ccl
    const int*   CJ = (const int*)d_in[3];     // y_ccl
    double* part = (double*)d_ws;              // 6 * 2048 doubles = 96 KiB (SoA)

    dim3 grid(BPB, NB);
    ncc_partial<<<grid, TPB, 0, stream>>>(I, J, CI, CJ, part);
    ncc_final<<<1, 1024, 0, stream>>>(part, (float*)d_out);
}

// Round 11
// 214.992 us; speedup vs baseline: 1.1354x; 1.1354x over previous
//
#include <hip/hip_runtime.h>

// NCC loss, Round 11: R8 reference-shape kernel + NONTEMPORAL loads.
// Fix vs R10: __builtin_nontemporal_load requires clang ext_vector_type,
// not HIP_vector_type (float4/int4) -> use native vector typedefs.
// Theory unchanged: 5 structures pin at ~95us; L2/L3-resident replays run at
// the SAME speed -> per-CU read-request/MSHR ceiling (~11 GB/s/CU), not HBM.
// nt bypasses L1 allocation; zero reuse makes nt semantically right anyway.

#define NB   16
#define VOL  (64 * 128 * 128)     // 1048576 elems per batch
#define BPB  128                  // blocks per batch (grid.x) -> 2048 total
#define TPB  256
#define ITER 8                    // iterations per thread
#define NPB  (NB * BPB)           // 2048 block-partial slots

static_assert((long long)BPB * TPB * 4 * ITER == (long long)VOL, "coverage");

typedef float f32x4 __attribute__((ext_vector_type(4)));
typedef int   i32x4 __attribute__((ext_vector_type(4)));

__device__ __forceinline__ double wave_reduce(double v) {
#pragma unroll
    for (int off = 32; off > 0; off >>= 1) v += __shfl_down(v, off, 64);
    return v;
}

// f32 threshold TH such that (f32 x < TH) <=> ((double)x < 0.247) exactly.
__device__ __forceinline__ float mask_thresh() {
    const float c = 0.247f;
    if ((double)c < 0.247) return __uint_as_float(__float_as_uint(c) + 1u);
    return c;
}

__global__ __launch_bounds__(TPB) void ncc_partial(
    const float* __restrict__ I, const float* __restrict__ J,
    const int* __restrict__ CI, const int* __restrict__ CJ,
    double* __restrict__ part)
{
    const int b = blockIdx.y, bx = blockIdx.x;
    const int tid = threadIdx.x;

    const f32x4* __restrict__ I4 = reinterpret_cast<const f32x4*>(I);
    const f32x4* __restrict__ J4 = reinterpret_cast<const f32x4*>(J);
    const i32x4* __restrict__ C4 = reinterpret_cast<const i32x4*>(CI);
    const i32x4* __restrict__ D4 = reinterpret_cast<const i32x4*>(CJ);

    const size_t batchq = (size_t)b * (VOL / 4);
    const float TH = mask_thresh();

    double aI = 0, aJ = 0, aI2 = 0, aJ2 = 0, aIJ = 0;
    int cnt = 0;

#pragma unroll
    for (int it = 0; it < ITER; ++it) {
        // stride = BPB*TPB quads (512 KB per array per iteration), coalesced
        const size_t q = batchq + (size_t)it * (BPB * TPB) + (size_t)bx * TPB + tid;
        f32x4 iv = __builtin_nontemporal_load(I4 + q);
        f32x4 jv = __builtin_nontemporal_load(J4 + q);
        i32x4 cv = __builtin_nontemporal_load(C4 + q);
        i32x4 dv = __builtin_nontemporal_load(D4 + q);

        float pI  = (iv.x + iv.y) + (iv.z + iv.w);
        float pJ  = (jv.x + jv.y) + (jv.z + jv.w);
        float pI2 = fmaf(iv.x, iv.x, fmaf(iv.y, iv.y, fmaf(iv.z, iv.z, iv.w * iv.w)));
        float pJ2 = fmaf(jv.x, jv.x, fmaf(jv.y, jv.y, fmaf(jv.z, jv.z, jv.w * jv.w)));
        float pIJ = fmaf(iv.x, jv.x, fmaf(iv.y, jv.y, fmaf(iv.z, jv.z, iv.w * jv.w)));

        int pc = 0;
        bool zI, zJ;
        zI = (iv.x < TH) && (cv.x > 0); zJ = (jv.x < TH) && (dv.x > 0); pc += (!zI && !zJ);
        zI = (iv.y < TH) && (cv.y > 0); zJ = (jv.y < TH) && (dv.y > 0); pc += (!zI && !zJ);
        zI = (iv.z < TH) && (cv.z > 0); zJ = (jv.z < TH) && (dv.z > 0); pc += (!zI && !zJ);
        zI = (iv.w < TH) && (cv.w > 0); zJ = (jv.w < TH) && (dv.w > 0); pc += (!zI && !zJ);

        aI  += (double)pI;
        aJ  += (double)pJ;
        aI2 += (double)pI2;
        aJ2 += (double)pJ2;
        aIJ += (double)pIJ;
        cnt += pc;
    }

    double v[6] = {aI, aJ, aI2, aJ2, aIJ, (double)cnt};
#pragma unroll
    for (int q = 0; q < 6; ++q) v[q] = wave_reduce(v[q]);

    __shared__ double sh[TPB / 64][6];
    const int wave = tid >> 6, lane = tid & 63;
    if (lane == 0) {
#pragma unroll
        for (int q = 0; q < 6; ++q) sh[wave][q] = v[q];
    }
    __syncthreads();

    if (tid == 0) {
        const int gb = b * BPB + bx;
#pragma unroll
        for (int q = 0; q < 6; ++q) {
            double o = 0.0;
            for (int w = 0; w < TPB / 64; ++w) o += sh[w][q];
            part[(size_t)q * NPB + gb] = o;   // SoA: coalesced for final pass
        }
    }
}

__global__ __launch_bounds__(1024) void ncc_final(
    const double* __restrict__ part, float* __restrict__ outp)
{
    const int tid = threadIdx.x;
    const int w = tid >> 6;     // wave w <-> batch w (16 waves)
    const int l = tid & 63;

    // BPB=128 partials per batch: 2 per lane
    double v[6];
#pragma unroll
    for (int q = 0; q < 6; ++q) {
        const size_t base = (size_t)q * NPB + (size_t)w * BPB;
        v[q] = part[base + l] + part[base + 64 + l];
    }
#pragma unroll
    for (int q = 0; q < 6; ++q) v[q] = wave_reduce(v[q]);

    __shared__ double acc[NB];
    if (l == 0) {
        const double W = (double)VOL;
        double uI = v[0] / W, uJ = v[1] / W;
        double cross = v[4] - uJ * v[0] - uI * v[1] + uI * uJ * W;
        double Ivar  = v[2] - 2.0 * uI * v[0] + uI * uI * W;
        double Jvar  = v[3] - 2.0 * uJ * v[1] + uJ * uJ * W;
        double cc = (cross * cross) / (Ivar * Jvar + 1e-5);
        acc[w] = -cc * v[5];
    }
    __syncthreads();

    if (tid == 0) {
        double t = 0.0;
        for (int b = 0; b < NB; ++b) t += acc[b];
        outp[0] = (float)(t / ((double)NB * (double)VOL));
    }
}

extern "C" void kernel_launch(void* const* d_in, const int* in_sizes, int n_in,
                              void* d_out, int out_size, void* d_ws, size_t ws_size,
                              hipStream_t stream)
{
    const float* I  = (const float*)d_in[0];   // out
    const float* J  = (const float*)d_in[1];   // y_pred
    const int*   CI = (const int*)d_in[2];     // out_ccl
    const int*   CJ = (const int*)d_in[3];     // y_ccl
    double* part = (double*)d_ws;              // 6 * 2048 doubles = 96 KiB (SoA)

    dim3 grid(BPB, NB);
    ncc_partial<<<grid, TPB, 0, stream>>>(I, J, CI, CJ, part);
    ncc_final<<<1, 1024, 0, stream>>>(part, (float*)d_out);
}